// Round 1
// baseline (254.905 us; speedup 1.0000x reference)
//
#include <hip/hip_runtime.h>
#include <hip/hip_bf16.h>
#include <math.h>

#define B_ 8
#define T_ 2048
#define C_ 1024
#define D_ 128
#define M_ (B_*T_)

typedef __attribute__((ext_vector_type(8))) short short8;
typedef __attribute__((ext_vector_type(4))) float floatx4;
typedef __hip_bfloat16 bf16;

// ---------------- W transpose + bf16 convert: Wt[g][n][k] = W_g[k][n] ----------------
__global__ __launch_bounds__(256) void cvt_w_kernel(const float* __restrict__ Wq,
                                                    const float* __restrict__ Wk,
                                                    const float* __restrict__ Wv,
                                                    bf16* __restrict__ Wt) {
    int i = blockIdx.x * 256 + threadIdx.x;      // 0 .. 3*131072-1
    int g = i >> 17;
    int r = i & 131071;                          // r = k*128 + n
    int k = r >> 7, n = r & 127;
    const float* W = (g == 0) ? Wq : (g == 1) ? Wk : Wv;
    Wt[g * 131072 + n * 1024 + k] = __float2bfloat16(W[r]);
}

// ---------------- QKV projection: out = x @ W, 64x128 tile, MFMA bf16 ----------------
// grid (M/64, 3): y==0 -> Qb, y==1 -> Kb, y==2 -> Vt (transposed [b][d][t])
__global__ __launch_bounds__(256) void proj_kernel(const float* __restrict__ x,
                                                   const bf16* __restrict__ Wt,
                                                   bf16* __restrict__ Qb,
                                                   bf16* __restrict__ Kb,
                                                   bf16* __restrict__ Vt) {
    __shared__ bf16 lds_x[64][40];    // 64 rows x 32 k (pad->40: 20-bank stride, ~2-way)
    __shared__ bf16 lds_w[128][40];   // 128 n x 32 k
    const int t = threadIdx.x;
    const int wave = t >> 6, lane = t & 63;
    const int quad = lane >> 4, l15 = lane & 15;
    const int g = blockIdx.y;
    const int row0 = blockIdx.x * 64;
    const bf16* wbase = Wt + g * 131072;

    floatx4 acc[8];
#pragma unroll
    for (int i = 0; i < 8; ++i) acc[i] = (floatx4)0.0f;

    for (int kc = 0; kc < 32; ++kc) {
        // stage x tile (fp32 -> bf16): 64 rows x 32 cols
        {
            int r = t >> 2, o = (t & 3) * 8;
            const float* src = x + (row0 + r) * 1024 + kc * 32 + o;
            float4 v0 = *(const float4*)src;
            float4 v1 = *(const float4*)(src + 4);
            union { short8 s; __hip_bfloat162 h[4]; } u;
            __hip_bfloat162 h;
            h.x = __float2bfloat16(v0.x); h.y = __float2bfloat16(v0.y); u.h[0] = h;
            h.x = __float2bfloat16(v0.z); h.y = __float2bfloat16(v0.w); u.h[1] = h;
            h.x = __float2bfloat16(v1.x); h.y = __float2bfloat16(v1.y); u.h[2] = h;
            h.x = __float2bfloat16(v1.z); h.y = __float2bfloat16(v1.w); u.h[3] = h;
            *(short8*)&lds_x[r][o] = u.s;
        }
        // stage W^T tile: 128 n-rows x 32 k
#pragma unroll
        for (int cc = 0; cc < 2; ++cc) {
            int c = t + cc * 256;
            int n = c >> 2, o = (c & 3) * 8;
            *(short8*)&lds_w[n][o] = *(const short8*)(wbase + n * 1024 + kc * 32 + o);
        }
        __syncthreads();
        short8 a = *(const short8*)&lds_x[wave * 16 + l15][quad * 8];
#pragma unroll
        for (int nt = 0; nt < 8; ++nt) {
            short8 b = *(const short8*)&lds_w[nt * 16 + l15][quad * 8];
            acc[nt] = __builtin_amdgcn_mfma_f32_16x16x32_bf16(a, b, acc[nt], 0, 0, 0);
        }
        __syncthreads();
    }

    // epilogue: C layout col = lane&15, row = quad*4 + reg
    const int qr = row0 + wave * 16 + quad * 4;
    if (g < 2) {
        bf16* outp = (g == 0) ? Qb : Kb;
#pragma unroll
        for (int nt = 0; nt < 8; ++nt)
#pragma unroll
            for (int r = 0; r < 4; ++r)
                outp[(qr + r) * 128 + nt * 16 + l15] = __float2bfloat16(acc[nt][r]);
    } else {
#pragma unroll
        for (int nt = 0; nt < 8; ++nt)
#pragma unroll
            for (int r = 0; r < 4; ++r) {
                int tq = qr + r;
                int bb = tq >> 11, tt = tq & 2047;
                int d = nt * 16 + l15;
                Vt[bb * (D_ * T_) + d * T_ + tt] = __float2bfloat16(acc[nt][r]);
            }
    }
}

// ---------------- flash attention: causal, online softmax ----------------
// grid (T/64, B); 4 waves x 16 q-rows each; 32-key chunks
__global__ __launch_bounds__(256) void flash_kernel(const bf16* __restrict__ Qb,
                                                    const bf16* __restrict__ Kb,
                                                    const bf16* __restrict__ Vt,
                                                    float* __restrict__ out) {
    __shared__ bf16 lds_k[32][136];   // 32 keys x 128 d (pad 136)
    __shared__ bf16 lds_v[128][40];   // 128 d x 32 keys (pad 40)
    __shared__ bf16 lds_p[4][16][40]; // per-wave P buffer (C->A layout round trip)
    const int t = threadIdx.x;
    const int wave = t >> 6, lane = t & 63;
    const int quad = lane >> 4, l15 = lane & 15;
    const int b = blockIdx.y;
    const int q0 = blockIdx.x * 64;
    const float scale = 0.08838834764831845f;   // 128^-0.5

    // Q fragments straight from global (A layout: m=lane&15, k=quad*8+j)
    short8 qf[4];
    {
        int qrow_f = q0 + wave * 16 + l15;
#pragma unroll
        for (int dk = 0; dk < 4; ++dk)
            qf[dk] = *(const short8*)(Qb + (b * T_ + qrow_f) * 128 + dk * 32 + quad * 8);
    }

    floatx4 o_acc[8];
#pragma unroll
    for (int i = 0; i < 8; ++i) o_acc[i] = (floatx4)0.0f;
    float m_i[4] = {-INFINITY, -INFINITY, -INFINITY, -INFINITY};
    float l_i[4] = {0.f, 0.f, 0.f, 0.f};

    const int wave_qmin = q0 + wave * 16;
    const int wave_qmax = wave_qmin + 15;
    const int qrow = wave_qmin + quad * 4;
    const int nchunk = (q0 + 64) >> 5;

    for (int kc = 0; kc < nchunk; ++kc) {
        const int k0 = kc << 5;
        // stage K chunk [32 keys][128 d] and V^T chunk [128 d][32 keys]
#pragma unroll
        for (int cc = 0; cc < 2; ++cc) {
            int c = t + cc * 256;
            { int r = c >> 4, o = (c & 15) * 8;
              *(short8*)&lds_k[r][o] = *(const short8*)(Kb + (b * T_ + k0 + r) * 128 + o); }
            { int d = c >> 2, o = (c & 3) * 8;
              *(short8*)&lds_v[d][o] = *(const short8*)(Vt + b * (D_ * T_) + d * T_ + k0 + o); }
        }
        __syncthreads();

        if (k0 <= wave_qmax) {
            // S = Q K^T : 2 n-tiles of 16 keys, 4 k-chunks of d
            floatx4 s0 = (floatx4)0.0f, s1 = (floatx4)0.0f;
#pragma unroll
            for (int dk = 0; dk < 4; ++dk) {
                short8 kb0 = *(const short8*)&lds_k[l15][dk * 32 + quad * 8];
                short8 kb1 = *(const short8*)&lds_k[16 + l15][dk * 32 + quad * 8];
                s0 = __builtin_amdgcn_mfma_f32_16x16x32_bf16(qf[dk], kb0, s0, 0, 0, 0);
                s1 = __builtin_amdgcn_mfma_f32_16x16x32_bf16(qf[dk], kb1, s1, 0, 0, 0);
            }
            float sv[2][4];
#pragma unroll
            for (int r = 0; r < 4; ++r) { sv[0][r] = s0[r] * scale; sv[1][r] = s1[r] * scale; }
            if (k0 + 31 > wave_qmin) {       // chunk touches the diagonal: mask
#pragma unroll
                for (int nt = 0; nt < 2; ++nt) {
                    int key = k0 + nt * 16 + l15;
#pragma unroll
                    for (int r = 0; r < 4; ++r)
                        if (key > qrow + r) sv[nt][r] = -1e30f;
                }
            }
            // row max over 32 keys (16 lanes hold the 16 cols of each row)
            float cmax[4], alpha[4], psum[4];
#pragma unroll
            for (int r = 0; r < 4; ++r) {
                float v = fmaxf(sv[0][r], sv[1][r]);
                v = fmaxf(v, __shfl_xor(v, 1));
                v = fmaxf(v, __shfl_xor(v, 2));
                v = fmaxf(v, __shfl_xor(v, 4));
                v = fmaxf(v, __shfl_xor(v, 8));
                cmax[r] = v;
            }
#pragma unroll
            for (int r = 0; r < 4; ++r) {
                float mn = fmaxf(m_i[r], cmax[r]);
                alpha[r] = __expf(m_i[r] - mn);
                m_i[r] = mn;
            }
#pragma unroll
            for (int nt = 0; nt < 2; ++nt)
#pragma unroll
                for (int r = 0; r < 4; ++r)
                    sv[nt][r] = __expf(sv[nt][r] - m_i[r]);
#pragma unroll
            for (int r = 0; r < 4; ++r) {
                float v = sv[0][r] + sv[1][r];
                v += __shfl_xor(v, 1);
                v += __shfl_xor(v, 2);
                v += __shfl_xor(v, 4);
                v += __shfl_xor(v, 8);
                psum[r] = v;
            }
#pragma unroll
            for (int r = 0; r < 4; ++r) l_i[r] = l_i[r] * alpha[r] + psum[r];
#pragma unroll
            for (int f = 0; f < 8; ++f)
#pragma unroll
                for (int r = 0; r < 4; ++r) o_acc[f][r] *= alpha[r];

            // P: C layout -> LDS -> A layout (wave-private, compiler inserts lgkmcnt)
#pragma unroll
            for (int nt = 0; nt < 2; ++nt)
#pragma unroll
                for (int r = 0; r < 4; ++r)
                    lds_p[wave][quad * 4 + r][nt * 16 + l15] = __float2bfloat16(sv[nt][r]);
            short8 pa = *(const short8*)&lds_p[wave][l15][quad * 8];

            // O += P V : 8 n-tiles of d, K=32 keys
#pragma unroll
            for (int nt = 0; nt < 8; ++nt) {
                short8 vb = *(const short8*)&lds_v[nt * 16 + l15][quad * 8];
                o_acc[nt] = __builtin_amdgcn_mfma_f32_16x16x32_bf16(pa, vb, o_acc[nt], 0, 0, 0);
            }
        }
        __syncthreads();
    }

    float inv_l[4];
#pragma unroll
    for (int r = 0; r < 4; ++r) inv_l[r] = 1.0f / l_i[r];
#pragma unroll
    for (int f = 0; f < 8; ++f)
#pragma unroll
        for (int r = 0; r < 4; ++r)
            out[(b * T_ + qrow + r) * 128 + f * 16 + l15] = o_acc[f][r] * inv_l[r];
}

extern "C" void kernel_launch(void* const* d_in, const int* in_sizes, int n_in,
                              void* d_out, int out_size, void* d_ws, size_t ws_size,
                              hipStream_t stream) {
    const float* x  = (const float*)d_in[0];
    const float* Wk = (const float*)d_in[1];
    const float* Wq = (const float*)d_in[2];
    const float* Wv = (const float*)d_in[3];
    float* out = (float*)d_out;

    char* ws = (char*)d_ws;
    bf16* Wt = (bf16*)ws;                          //   786,432 B  [3][128][1024]
    bf16* Qb = (bf16*)(ws + 786432);               // 4,194,304 B  [M][128]
    bf16* Kb = (bf16*)(ws + 786432 + 4194304);     // 4,194,304 B
    bf16* Vt = (bf16*)(ws + 786432 + 2*4194304);   // 4,194,304 B  [B][128][T]

    cvt_w_kernel<<<1536, 256, 0, stream>>>(Wq, Wk, Wv, Wt);
    proj_kernel<<<dim3(M_ / 64, 3), 256, 0, stream>>>(x, Wt, Qb, Kb, Vt);
    flash_kernel<<<dim3(T_ / 64, B_), 256, 0, stream>>>(Qb, Kb, Vt, out);
}

// Round 3
// 197.103 us; speedup vs baseline: 1.2933x; 1.2933x over previous
//
#include <hip/hip_runtime.h>
#include <hip/hip_bf16.h>
#include <math.h>

#define B_ 8
#define T_ 2048
#define C_ 1024
#define D_ 128
#define M_ (B_*T_)

typedef __attribute__((ext_vector_type(8))) short short8;
typedef __attribute__((ext_vector_type(4))) float floatx4;
typedef __hip_bfloat16 bf16;

// exp2 domain: Q pre-scaled by 128^-0.5 * log2(e)
#define QSCALE 0.12751744416218247f

// ---------------- W transpose + bf16 convert: Wt[g][n][k] = W_g[k][n] ----------------
__global__ __launch_bounds__(256) void cvt_w_kernel(const float* __restrict__ Wq,
                                                    const float* __restrict__ Wk,
                                                    const float* __restrict__ Wv,
                                                    bf16* __restrict__ Wt) {
    int i = blockIdx.x * 256 + threadIdx.x;
    int g = i >> 17;
    int r = i & 131071;
    int k = r >> 7, n = r & 127;
    const float* W = (g == 0) ? Wq : (g == 1) ? Wk : Wv;
    Wt[g * 131072 + n * 1024 + k] = __float2bfloat16(W[r]);
}

// ---------------- x fp32 -> bf16 ----------------
__global__ __launch_bounds__(256) void cvt_x_kernel(const float* __restrict__ x,
                                                    bf16* __restrict__ xb) {
    int i = blockIdx.x * 256 + threadIdx.x;   // one per 8 floats
    const float* src = x + (size_t)i * 8;
    float4 v0 = *(const float4*)src;
    float4 v1 = *(const float4*)(src + 4);
    union { short8 s; __hip_bfloat162 h[4]; } u;
    __hip_bfloat162 h;
    h.x = __float2bfloat16(v0.x); h.y = __float2bfloat16(v0.y); u.h[0] = h;
    h.x = __float2bfloat16(v0.z); h.y = __float2bfloat16(v0.w); u.h[1] = h;
    h.x = __float2bfloat16(v1.x); h.y = __float2bfloat16(v1.y); u.h[2] = h;
    h.x = __float2bfloat16(v1.z); h.y = __float2bfloat16(v1.w); u.h[3] = h;
    *(short8*)(xb + (size_t)i * 8) = u.s;
}

// ---------------- proj v2: 128x128 tile, BK=64, bf16 inputs ----------------
// grid (M/128, 3): y==0 -> Qb (pre-scaled), y==1 -> Kb, y==2 -> Vt [b][d][t]
__global__ __launch_bounds__(256) void proj2_kernel(const bf16* __restrict__ xb,
                                                    const bf16* __restrict__ Wt,
                                                    bf16* __restrict__ Qb,
                                                    bf16* __restrict__ Kb,
                                                    bf16* __restrict__ Vt) {
    __shared__ bf16 la[128][72];
    __shared__ bf16 lb[128][72];
    const int t = threadIdx.x;
    const int wave = t >> 6, lane = t & 63;
    const int quad = lane >> 4, l15 = lane & 15;
    const int wr = wave >> 1, wc = wave & 1;    // 64x64 quadrant per wave
    const int g = blockIdx.y;
    const int row0 = blockIdx.x * 128;
    const bf16* wbase = Wt + g * 131072;

    floatx4 acc[4][4];
#pragma unroll
    for (int m = 0; m < 4; ++m)
#pragma unroll
        for (int n = 0; n < 4; ++n) acc[m][n] = (floatx4)0.0f;

    for (int kc = 0; kc < 16; ++kc) {
        // stage 128 rows x 64 k, 8-elem chunks: 1024 chunks per buffer
#pragma unroll
        for (int j = 0; j < 4; ++j) {
            int c = t + j * 256;
            int r = c >> 3, co = (c & 7) * 8;
            *(short8*)&la[r][co] = *(const short8*)(xb + (size_t)(row0 + r) * 1024 + kc * 64 + co);
            *(short8*)&lb[r][co] = *(const short8*)(wbase + r * 1024 + kc * 64 + co);
        }
        __syncthreads();
#pragma unroll
        for (int dk = 0; dk < 2; ++dk) {
            short8 af[4], bff[4];
#pragma unroll
            for (int m = 0; m < 4; ++m) af[m] = *(const short8*)&la[wr * 64 + m * 16 + l15][dk * 32 + quad * 8];
#pragma unroll
            for (int n = 0; n < 4; ++n) bff[n] = *(const short8*)&lb[wc * 64 + n * 16 + l15][dk * 32 + quad * 8];
#pragma unroll
            for (int m = 0; m < 4; ++m)
#pragma unroll
                for (int n = 0; n < 4; ++n)
                    acc[m][n] = __builtin_amdgcn_mfma_f32_16x16x32_bf16(af[m], bff[n], acc[m][n], 0, 0, 0);
        }
        __syncthreads();
    }

    const float qs = (g == 0) ? QSCALE : 1.0f;
#pragma unroll
    for (int m = 0; m < 4; ++m)
#pragma unroll
        for (int r = 0; r < 4; ++r) {
            int row = row0 + wr * 64 + m * 16 + quad * 4 + r;
            if (g < 2) {
                bf16* outp = g ? Kb : Qb;
#pragma unroll
                for (int n = 0; n < 4; ++n)
                    outp[(size_t)row * 128 + wc * 64 + n * 16 + l15] = __float2bfloat16(acc[m][n][r] * qs);
            } else {
                int bb = row >> 11, tt = row & 2047;
#pragma unroll
                for (int n = 0; n < 4; ++n)
                    Vt[(size_t)bb * (D_ * T_) + (wc * 64 + n * 16 + l15) * T_ + tt] = __float2bfloat16(acc[m][n][r]);
            }
        }
}

// ---------------- split-K flash: grid (32 tiles, 4 segs, 8 batches) ----------------
// segment = 512 keys; 64-key chunks; 4 waves x 16 q-rows
__global__ __launch_bounds__(256) void flash_split_kernel(const bf16* __restrict__ Qb,
                                                          const bf16* __restrict__ Kb,
                                                          const bf16* __restrict__ Vt,
                                                          float* __restrict__ out,
                                                          float* __restrict__ Opart,
                                                          float* __restrict__ Mpart,
                                                          float* __restrict__ Lpart) {
    const int tile = blockIdx.x, seg = blockIdx.y, b = blockIdx.z;
    const int keys_total = (tile + 1) * 64;
    const int nseg = (keys_total + 511) >> 9;
    if (seg >= nseg) return;

    __shared__ bf16 lds_k[64][136];
    __shared__ bf16 lds_v[128][72];
    __shared__ bf16 lds_p[4][16][72];
    const int t = threadIdx.x;
    const int wave = t >> 6, lane = t & 63;
    const int quad = lane >> 4, l15 = lane & 15;
    const int q0 = tile * 64;
    const int k_start = seg << 9;
    const int k_end = min(k_start + 512, keys_total);
    const int nch = (k_end - k_start) >> 6;

    short8 qf[4];
    {
        int qm = q0 + wave * 16 + l15;
#pragma unroll
        for (int dk = 0; dk < 4; ++dk)
            qf[dk] = *(const short8*)(Qb + (size_t)(b * T_ + qm) * 128 + dk * 32 + quad * 8);
    }

    floatx4 o_acc[8];
#pragma unroll
    for (int i = 0; i < 8; ++i) o_acc[i] = (floatx4)0.0f;
    float m_i[4] = {-INFINITY, -INFINITY, -INFINITY, -INFINITY};
    float l_i[4] = {0.f, 0.f, 0.f, 0.f};
    const int qrow = q0 + wave * 16 + quad * 4;

    for (int ch = 0; ch < nch; ++ch) {
        const int k0 = k_start + (ch << 6);
        // stage K chunk [64 keys][128 d] (1024 chunks) and V^T [128 d][64 keys] (1024 chunks)
#pragma unroll
        for (int j = 0; j < 4; ++j) {
            int c = t + j * 256;
            { int r = c >> 4, co = (c & 15) * 8;
              *(short8*)&lds_k[r][co] = *(const short8*)(Kb + (size_t)(b * T_ + k0 + r) * 128 + co); }
            { int d = c >> 3, co = (c & 7) * 8;
              *(short8*)&lds_v[d][co] = *(const short8*)(Vt + (size_t)b * (D_ * T_) + d * T_ + k0 + co); }
        }
        __syncthreads();

        floatx4 s[4];
#pragma unroll
        for (int nt = 0; nt < 4; ++nt) s[nt] = (floatx4)0.0f;
#pragma unroll
        for (int dk = 0; dk < 4; ++dk)
#pragma unroll
            for (int nt = 0; nt < 4; ++nt) {
                short8 kb = *(const short8*)&lds_k[nt * 16 + l15][dk * 32 + quad * 8];
                s[nt] = __builtin_amdgcn_mfma_f32_16x16x32_bf16(qf[dk], kb, s[nt], 0, 0, 0);
            }

        float sv[4][4];
#pragma unroll
        for (int nt = 0; nt < 4; ++nt)
#pragma unroll
            for (int r = 0; r < 4; ++r) sv[nt][r] = s[nt][r];

        if (k0 + 63 > q0) {   // only the diagonal chunk
#pragma unroll
            for (int nt = 0; nt < 4; ++nt) {
                int key = k0 + nt * 16 + l15;
#pragma unroll
                for (int r = 0; r < 4; ++r)
                    if (key > qrow + r) sv[nt][r] = -1e30f;
            }
        }

        float alpha[4];
#pragma unroll
        for (int r = 0; r < 4; ++r) {
            float v = fmaxf(fmaxf(sv[0][r], sv[1][r]), fmaxf(sv[2][r], sv[3][r]));
            v = fmaxf(v, __shfl_xor(v, 1));
            v = fmaxf(v, __shfl_xor(v, 2));
            v = fmaxf(v, __shfl_xor(v, 4));
            v = fmaxf(v, __shfl_xor(v, 8));
            float mn = fmaxf(m_i[r], v);
            alpha[r] = exp2f(m_i[r] - mn);
            m_i[r] = mn;
        }
#pragma unroll
        for (int nt = 0; nt < 4; ++nt)
#pragma unroll
            for (int r = 0; r < 4; ++r) sv[nt][r] = exp2f(sv[nt][r] - m_i[r]);
#pragma unroll
        for (int r = 0; r < 4; ++r) {
            float v = sv[0][r] + sv[1][r] + sv[2][r] + sv[3][r];
            v += __shfl_xor(v, 1);
            v += __shfl_xor(v, 2);
            v += __shfl_xor(v, 4);
            v += __shfl_xor(v, 8);
            l_i[r] = l_i[r] * alpha[r] + v;
        }
#pragma unroll
        for (int f = 0; f < 8; ++f)
#pragma unroll
            for (int r = 0; r < 4; ++r) o_acc[f][r] *= alpha[r];

        // P: C layout -> LDS -> A layout (wave-private)
#pragma unroll
        for (int nt = 0; nt < 4; ++nt)
#pragma unroll
            for (int r = 0; r < 4; ++r)
                lds_p[wave][quad * 4 + r][nt * 16 + l15] = __float2bfloat16(sv[nt][r]);
        short8 pa0 = *(const short8*)&lds_p[wave][l15][quad * 8];
        short8 pa1 = *(const short8*)&lds_p[wave][l15][32 + quad * 8];

#pragma unroll
        for (int nt = 0; nt < 8; ++nt) {
            short8 vb0 = *(const short8*)&lds_v[nt * 16 + l15][quad * 8];
            short8 vb1 = *(const short8*)&lds_v[nt * 16 + l15][32 + quad * 8];
            o_acc[nt] = __builtin_amdgcn_mfma_f32_16x16x32_bf16(pa0, vb0, o_acc[nt], 0, 0, 0);
            o_acc[nt] = __builtin_amdgcn_mfma_f32_16x16x32_bf16(pa1, vb1, o_acc[nt], 0, 0, 0);
        }
        __syncthreads();
    }

    const int lrow = wave * 16 + quad * 4;    // local row within tile
    if (nseg == 1) {
        float inv_l[4];
#pragma unroll
        for (int r = 0; r < 4; ++r) inv_l[r] = 1.0f / l_i[r];
#pragma unroll
        for (int f = 0; f < 8; ++f)
#pragma unroll
            for (int r = 0; r < 4; ++r)
                out[(size_t)(b * T_ + qrow + r) * 128 + f * 16 + l15] = o_acc[f][r] * inv_l[r];
    } else {
        size_t base = ((size_t)(b * 32 + tile) * 4 + seg) * 64;
#pragma unroll
        for (int f = 0; f < 8; ++f)
#pragma unroll
            for (int r = 0; r < 4; ++r)
                Opart[(base + lrow + r) * 128 + f * 16 + l15] = o_acc[f][r];
        if (l15 == 0) {
#pragma unroll
            for (int r = 0; r < 4; ++r) {
                Mpart[base + lrow + r] = m_i[r];
                Lpart[base + lrow + r] = l_i[r];
            }
        }
    }
}

// ---------------- combine partials ----------------
__global__ __launch_bounds__(256) void combine_kernel(const float* __restrict__ Opart,
                                                      const float* __restrict__ Mpart,
                                                      const float* __restrict__ Lpart,
                                                      float* __restrict__ out) {
    const int tile = blockIdx.x, b = blockIdx.y;
    const int nseg = ((tile + 1) * 64 + 511) >> 9;
    if (nseg < 2) return;
    const int t = threadIdx.x;
    const int row = t >> 2, c0 = (t & 3) * 32;
    const size_t tbase = ((size_t)(b * 32 + tile)) * 4;

    float mstar = -INFINITY;
    float mv[4];
    for (int j = 0; j < nseg; ++j) {
        mv[j] = Mpart[(tbase + j) * 64 + row];
        mstar = fmaxf(mstar, mv[j]);
    }
    float lstar = 0.f, w[4];
    for (int j = 0; j < nseg; ++j) {
        w[j] = exp2f(mv[j] - mstar);
        lstar += w[j] * Lpart[(tbase + j) * 64 + row];
    }
    float4 acc4[8];
#pragma unroll
    for (int u = 0; u < 8; ++u) acc4[u] = make_float4(0.f, 0.f, 0.f, 0.f);
    for (int j = 0; j < nseg; ++j) {
        const float4* src = (const float4*)(Opart + ((tbase + j) * 64 + row) * 128 + c0);
        float wj = w[j];
#pragma unroll
        for (int u = 0; u < 8; ++u) {
            float4 v = src[u];
            acc4[u].x += wj * v.x; acc4[u].y += wj * v.y;
            acc4[u].z += wj * v.z; acc4[u].w += wj * v.w;
        }
    }
    float inv = 1.0f / lstar;
    float4* dst = (float4*)(out + ((size_t)b * T_ + tile * 64 + row) * 128 + c0);
#pragma unroll
    for (int u = 0; u < 8; ++u) {
        float4 v = acc4[u];
        v.x *= inv; v.y *= inv; v.z *= inv; v.w *= inv;
        dst[u] = v;
    }
}

// ================= fallback path (round-1 kernels, needs only 13.4 MB ws) =================
__global__ __launch_bounds__(256) void proj_fb_kernel(const float* __restrict__ x,
                                                      const bf16* __restrict__ Wt,
                                                      bf16* __restrict__ Qb,
                                                      bf16* __restrict__ Kb,
                                                      bf16* __restrict__ Vt) {
    __shared__ bf16 lds_x[64][40];
    __shared__ bf16 lds_w[128][40];
    const int t = threadIdx.x;
    const int wave = t >> 6, lane = t & 63;
    const int quad = lane >> 4, l15 = lane & 15;
    const int g = blockIdx.y;
    const int row0 = blockIdx.x * 64;
    const bf16* wbase = Wt + g * 131072;
    floatx4 acc[8];
#pragma unroll
    for (int i = 0; i < 8; ++i) acc[i] = (floatx4)0.0f;
    for (int kc = 0; kc < 32; ++kc) {
        {
            int r = t >> 2, o = (t & 3) * 8;
            const float* src = x + (size_t)(row0 + r) * 1024 + kc * 32 + o;
            float4 v0 = *(const float4*)src;
            float4 v1 = *(const float4*)(src + 4);
            union { short8 s; __hip_bfloat162 h[4]; } u;
            __hip_bfloat162 h;
            h.x = __float2bfloat16(v0.x); h.y = __float2bfloat16(v0.y); u.h[0] = h;
            h.x = __float2bfloat16(v0.z); h.y = __float2bfloat16(v0.w); u.h[1] = h;
            h.x = __float2bfloat16(v1.x); h.y = __float2bfloat16(v1.y); u.h[2] = h;
            h.x = __float2bfloat16(v1.z); h.y = __float2bfloat16(v1.w); u.h[3] = h;
            *(short8*)&lds_x[r][o] = u.s;
        }
#pragma unroll
        for (int cc = 0; cc < 2; ++cc) {
            int c = t + cc * 256;
            int n = c >> 2, o = (c & 3) * 8;
            *(short8*)&lds_w[n][o] = *(const short8*)(wbase + n * 1024 + kc * 32 + o);
        }
        __syncthreads();
        short8 a = *(const short8*)&lds_x[wave * 16 + l15][quad * 8];
#pragma unroll
        for (int nt = 0; nt < 8; ++nt) {
            short8 bfr = *(const short8*)&lds_w[nt * 16 + l15][quad * 8];
            acc[nt] = __builtin_amdgcn_mfma_f32_16x16x32_bf16(a, bfr, acc[nt], 0, 0, 0);
        }
        __syncthreads();
    }
    const int qr = row0 + wave * 16 + quad * 4;
    if (g < 2) {
        bf16* outp = (g == 0) ? Qb : Kb;
#pragma unroll
        for (int nt = 0; nt < 8; ++nt)
#pragma unroll
            for (int r = 0; r < 4; ++r)
                outp[(size_t)(qr + r) * 128 + nt * 16 + l15] = __float2bfloat16(acc[nt][r]);
    } else {
#pragma unroll
        for (int nt = 0; nt < 8; ++nt)
#pragma unroll
            for (int r = 0; r < 4; ++r) {
                int tq = qr + r;
                int bb = tq >> 11, tt = tq & 2047;
                Vt[(size_t)bb * (D_ * T_) + (nt * 16 + l15) * T_ + tt] = __float2bfloat16(acc[nt][r]);
            }
    }
}

__global__ __launch_bounds__(256) void flash_fb_kernel(const bf16* __restrict__ Qb,
                                                       const bf16* __restrict__ Kb,
                                                       const bf16* __restrict__ Vt,
                                                       float* __restrict__ out) {
    __shared__ bf16 lds_k[32][136];
    __shared__ bf16 lds_v[128][40];
    __shared__ bf16 lds_p[4][16][40];
    const int t = threadIdx.x;
    const int wave = t >> 6, lane = t & 63;
    const int quad = lane >> 4, l15 = lane & 15;
    const int b = blockIdx.y;
    const int q0 = blockIdx.x * 64;
    const float scale = 0.08838834764831845f;
    short8 qf[4];
    {
        int qrow_f = q0 + wave * 16 + l15;
#pragma unroll
        for (int dk = 0; dk < 4; ++dk)
            qf[dk] = *(const short8*)(Qb + (size_t)(b * T_ + qrow_f) * 128 + dk * 32 + quad * 8);
    }
    floatx4 o_acc[8];
#pragma unroll
    for (int i = 0; i < 8; ++i) o_acc[i] = (floatx4)0.0f;
    float m_i[4] = {-INFINITY, -INFINITY, -INFINITY, -INFINITY};
    float l_i[4] = {0.f, 0.f, 0.f, 0.f};
    const int wave_qmin = q0 + wave * 16;
    const int wave_qmax = wave_qmin + 15;
    const int qrow = wave_qmin + quad * 4;
    const int nchunk = (q0 + 64) >> 5;
    for (int kc = 0; kc < nchunk; ++kc) {
        const int k0 = kc << 5;
#pragma unroll
        for (int cc = 0; cc < 2; ++cc) {
            int c = t + cc * 256;
            { int r = c >> 4, o = (c & 15) * 8;
              *(short8*)&lds_k[r][o] = *(const short8*)(Kb + (size_t)(b * T_ + k0 + r) * 128 + o); }
            { int d = c >> 2, o = (c & 3) * 8;
              *(short8*)&lds_v[d][o] = *(const short8*)(Vt + (size_t)b * (D_ * T_) + d * T_ + k0 + o); }
        }
        __syncthreads();
        if (k0 <= wave_qmax) {
            floatx4 s0 = (floatx4)0.0f, s1 = (floatx4)0.0f;
#pragma unroll
            for (int dk = 0; dk < 4; ++dk) {
                short8 kb0 = *(const short8*)&lds_k[l15][dk * 32 + quad * 8];
                short8 kb1 = *(const short8*)&lds_k[16 + l15][dk * 32 + quad * 8];
                s0 = __builtin_amdgcn_mfma_f32_16x16x32_bf16(qf[dk], kb0, s0, 0, 0, 0);
                s1 = __builtin_amdgcn_mfma_f32_16x16x32_bf16(qf[dk], kb1, s1, 0, 0, 0);
            }
            float sv[2][4];
#pragma unroll
            for (int r = 0; r < 4; ++r) { sv[0][r] = s0[r] * scale; sv[1][r] = s1[r] * scale; }
            if (k0 + 31 > wave_qmin) {
#pragma unroll
                for (int nt = 0; nt < 2; ++nt) {
                    int key = k0 + nt * 16 + l15;
#pragma unroll
                    for (int r = 0; r < 4; ++r)
                        if (key > qrow + r) sv[nt][r] = -1e30f;
                }
            }
            float alpha[4];
#pragma unroll
            for (int r = 0; r < 4; ++r) {
                float v = fmaxf(sv[0][r], sv[1][r]);
                v = fmaxf(v, __shfl_xor(v, 1));
                v = fmaxf(v, __shfl_xor(v, 2));
                v = fmaxf(v, __shfl_xor(v, 4));
                v = fmaxf(v, __shfl_xor(v, 8));
                float mn = fmaxf(m_i[r], v);
                alpha[r] = __expf(m_i[r] - mn);
                m_i[r] = mn;
            }
#pragma unroll
            for (int nt = 0; nt < 2; ++nt)
#pragma unroll
                for (int r = 0; r < 4; ++r) sv[nt][r] = __expf(sv[nt][r] - m_i[r]);
#pragma unroll
            for (int r = 0; r < 4; ++r) {
                float v = sv[0][r] + sv[1][r];
                v += __shfl_xor(v, 1);
                v += __shfl_xor(v, 2);
                v += __shfl_xor(v, 4);
                v += __shfl_xor(v, 8);
                l_i[r] = l_i[r] * alpha[r] + v;
            }
#pragma unroll
            for (int f = 0; f < 8; ++f)
#pragma unroll
                for (int r = 0; r < 4; ++r) o_acc[f][r] *= alpha[r];
#pragma unroll
            for (int nt = 0; nt < 2; ++nt)
#pragma unroll
                for (int r = 0; r < 4; ++r)
                    lds_p[wave][quad * 4 + r][nt * 16 + l15] = __float2bfloat16(sv[nt][r]);
            short8 pa = *(const short8*)&lds_p[wave][l15][quad * 8];
#pragma unroll
            for (int nt = 0; nt < 8; ++nt) {
                short8 vb = *(const short8*)&lds_v[nt * 16 + l15][quad * 8];
                o_acc[nt] = __builtin_amdgcn_mfma_f32_16x16x32_bf16(pa, vb, o_acc[nt], 0, 0, 0);
            }
        }
        __syncthreads();
    }
    float inv_l[4];
#pragma unroll
    for (int r = 0; r < 4; ++r) inv_l[r] = 1.0f / l_i[r];
#pragma unroll
    for (int f = 0; f < 8; ++f)
#pragma unroll
        for (int r = 0; r < 4; ++r)
            out[(size_t)(b * T_ + qrow + r) * 128 + f * 16 + l15] = o_acc[f][r] * inv_l[r];
}

extern "C" void kernel_launch(void* const* d_in, const int* in_sizes, int n_in,
                              void* d_out, int out_size, void* d_ws, size_t ws_size,
                              hipStream_t stream) {
    const float* x  = (const float*)d_in[0];
    const float* Wk = (const float*)d_in[1];
    const float* Wq = (const float*)d_in[2];
    const float* Wv = (const float*)d_in[3];
    float* out = (float*)d_out;

    char* ws = (char*)d_ws;
    bf16* Wt = (bf16*)ws;                           //  786,432 B
    bf16* Qb = (bf16*)(ws + 786432);                //  4 MB
    bf16* Kb = (bf16*)(ws + 4980736);               //  4 MB
    bf16* Vt = (bf16*)(ws + 9175040);               //  4 MB -> ends 13369344

    const size_t NEED = 47448064ull;
    if (ws_size >= NEED) {
        bf16*  xb    = (bf16*)(ws + 13369344);      // 33,554,432 B (proj phase)
        float* Opart = (float*)(ws + 13369344);     // aliases xb (flash phase)
        float* Mpart = (float*)(ws + 46923776);     // 262,144 B
        float* Lpart = (float*)(ws + 47185920);     // 262,144 B

        cvt_w_kernel<<<1536, 256, 0, stream>>>(Wq, Wk, Wv, Wt);
        cvt_x_kernel<<<8192, 256, 0, stream>>>(x, xb);
        proj2_kernel<<<dim3(M_ / 128, 3), 256, 0, stream>>>(xb, Wt, Qb, Kb, Vt);
        flash_split_kernel<<<dim3(32, 4, B_), 256, 0, stream>>>(Qb, Kb, Vt, out, Opart, Mpart, Lpart);
        combine_kernel<<<dim3(32, B_), 256, 0, stream>>>(Opart, Mpart, Lpart, out);
    } else {
        cvt_w_kernel<<<1536, 256, 0, stream>>>(Wq, Wk, Wv, Wt);
        proj_fb_kernel<<<dim3(M_ / 64, 3), 256, 0, stream>>>(x, Wt, Qb, Kb, Vt);
        flash_fb_kernel<<<dim3(T_ / 64, B_), 256, 0, stream>>>(Qb, Kb, Vt, out);
    }
}